// Round 18
// baseline (181.072 us; speedup 1.0000x reference)
//
#include <hip/hip_runtime.h>

#define NN   6144
#define EE   98304
#define DIN  128
#define DD   256
#define TT   32
#define NH   4
#define ZQ   6
#define ZK   6
#define WROWS 3328

typedef __attribute__((ext_vector_type(8))) short short8;
typedef __attribute__((ext_vector_type(4))) float f32x4;
typedef unsigned short u16;

__device__ __forceinline__ float bf2f(u16 u) {
    return __uint_as_float(((unsigned)u) << 16);
}
__device__ __forceinline__ u16 f2bf(float f) {
    unsigned u = __float_as_uint(f);
    return (u16)((u + 0x7fffu + ((u >> 16) & 1u)) >> 16);
}
__device__ __forceinline__ unsigned pk2(float a, float b) {
    return (unsigned)f2bf(a) | ((unsigned)f2bf(b) << 16);
}
__device__ __forceinline__ float bnrelu(float v, float s, float q, float g, float b) {
    float mu = s * (1.0f / NN);
    float var = q * (1.0f / NN) - mu * mu;
    return fmaxf((v - mu) * rsqrtf(var + 1e-5f) * g + b, 0.0f);
}

// ---------------- CSR build ----------------
__global__ void aml_hist_k(const int* __restrict__ ei, int* __restrict__ deg) {
    int e = blockIdx.x * 256 + threadIdx.x;
    if (e < EE) atomicAdd(&deg[ei[EE + e]], 1);
}

__global__ void aml_scan_k(const int* __restrict__ deg, int* __restrict__ rowptr,
                           int* __restrict__ cursor) {
    int t = threadIdx.x;
    int base = t * 24;
    int loc[24];
    int s = 0;
    #pragma unroll
    for (int j = 0; j < 24; ++j) { loc[j] = s; s += deg[base + j]; }
    __shared__ int part[256];
    part[t] = s;
    __syncthreads();
    for (int o = 1; o < 256; o <<= 1) {
        int v = (t >= o) ? part[t - o] : 0;
        __syncthreads();
        part[t] += v;
        __syncthreads();
    }
    int off = (t > 0) ? part[t - 1] : 0;
    #pragma unroll
    for (int j = 0; j < 24; ++j) {
        rowptr[base + j] = off + loc[j];
        cursor[base + j] = off + loc[j];
    }
    if (t == 255) rowptr[NN] = part[255];
}

__global__ void aml_scatter2_k(const int* __restrict__ ei, int* __restrict__ cursor,
                               int* __restrict__ eid) {
    int e = blockIdx.x * 256 + threadIdx.x;
    if (e >= EE) return;
    int slot = atomicAdd(&cursor[ei[EE + e]], 1);
    eid[slot] = ei[e];
}

__global__ void aml_gather_k(const float* __restrict__ x, const int* __restrict__ rowptr,
                             const int* __restrict__ eid, u16* __restrict__ ac) {
    int node = blockIdx.x * 4 + (threadIdx.x >> 6);
    int lane = threadIdx.x & 63;
    int p0 = rowptr[node], p1 = rowptr[node + 1];
    float ax = 0.f, ay = 0.f;
    int j = p0;
    for (; j + 1 < p1; j += 2) {
        int s0 = eid[j], s1 = eid[j + 1];
        float2 v0 = *(const float2*)(x + (size_t)s0 * DIN + lane * 2);
        float2 v1 = *(const float2*)(x + (size_t)s1 * DIN + lane * 2);
        ax += v0.x + v1.x; ay += v0.y + v1.y;
    }
    if (j < p1) {
        float2 v = *(const float2*)(x + (size_t)eid[j] * DIN + lane * 2);
        ax += v.x; ay += v.y;
    }
    float inv = 1.0f / fmaxf((float)(p1 - p0), 1.0f);
    float2 xr = *(const float2*)(x + (size_t)node * DIN + lane * 2);
    *(unsigned*)(ac + (size_t)node * DD + lane * 2) = pk2(ax * inv, ay * inv);
    *(unsigned*)(ac + (size_t)node * DD + DIN + lane * 2) = pk2(xr.x, xr.y);
}

// ---------------- prep weights + segment offsets + zero stats/deg ----------------
__global__ void aml_prep_k(const float* __restrict__ lin_l_w, const float* __restrict__ lin_r_w,
                           const float* __restrict__ inp_w, const float* __restrict__ out_w,
                           const float* __restrict__ ff1_w, const float* __restrict__ ff2_w,
                           const int* __restrict__ ts, u16* __restrict__ wb,
                           int* __restrict__ offs, float* __restrict__ zero_region) {
    int r = blockIdx.x;
    if (r > WROWS) {
        zero_region[(r - WROWS - 1) * 256 + threadIdx.x] = 0.0f;
        return;
    }
    if (r == WROWS) {
        int t = threadIdx.x;
        if (t <= TT) {
            int lo = 0, hi = NN;
            while (lo < hi) { int mid = (lo + hi) >> 1; if (ts[mid] < t) lo = mid + 1; else hi = mid; }
            offs[t] = lo;
        }
        return;
    }
    int k = threadIdx.x;
    float v;
    if (r < 256) {
        v = (k < DIN) ? lin_l_w[r * DIN + k] : lin_r_w[r * DIN + (k - DIN)];
    } else {
        int r2 = r - 256;
        int l = r2 / 1536, r3 = r2 % 1536;
        const float* src; int rr;
        if (r3 < 768)       { src = inp_w + (size_t)l * 768 * DD; rr = r3; }
        else if (r3 < 1024) { src = out_w + (size_t)l * DD * DD;  rr = r3 - 768; }
        else if (r3 < 1280) { src = ff1_w + (size_t)l * DD * DD;  rr = r3 - 1024; }
        else                { src = ff2_w + (size_t)l * DD * DD;  rr = r3 - 1280; }
        v = src[(size_t)rr * DD + k];
    }
    wb[(size_t)r * DD + k] = f2bf(v);
}

// ---------------- MFMA GEMM (sage / qkv0), CT2=1 ----------------
template <int RELU, int AMODE, int CF32, int BNSTAT, int CT2>
__global__ __launch_bounds__(256)
void aml_gemm_k(const void* __restrict__ A, const u16* __restrict__ Wb,
                const float* __restrict__ bias, void* __restrict__ C, int M,
                float* __restrict__ stats, const float* __restrict__ bng,
                const float* __restrict__ bnb, float* __restrict__ h2) {
    __shared__ __align__(16) unsigned char lds[65536];
    const int t = threadIdx.x;
    const int brow = blockIdx.x * 64;
    const int bcol = blockIdx.y * (64 * CT2);

    #pragma unroll
    for (int p = 0; p < 8; ++p) {
        int c = t + p * 256;
        int row = c >> 5;
        int colb = (c & 31) * 16;
        int dst = row * 512 + (colb ^ ((row & 7) << 4));
        if (AMODE == 2) {
            int d0 = (c & 31) * 8;
            const u16* sA = (const u16*)A + (size_t)(brow + row) * 256 + d0;
            uint4 raw = *(const uint4*)sA;
            const u16* rp = (const u16*)&raw;
            float av[8];
            #pragma unroll
            for (int i = 0; i < 8; ++i) {
                int d = d0 + i;
                av[i] = bnrelu(bf2f(rp[i]), stats[d], stats[DD + d], bng[d], bnb[d]);
            }
            if (blockIdx.y == 0) {
                float* hp = h2 + (size_t)(brow + row) * 256 + d0;
                *(float4*)hp = make_float4(av[0], av[1], av[2], av[3]);
                *(float4*)(hp + 4) = make_float4(av[4], av[5], av[6], av[7]);
            }
            uint4 pa = { pk2(av[0], av[1]), pk2(av[2], av[3]), pk2(av[4], av[5]), pk2(av[6], av[7]) };
            *(uint4*)(lds + dst) = pa;
        } else {
            const u16* sA = (const u16*)A + (size_t)(brow + row) * 256 + (c & 31) * 8;
            *(uint4*)(lds + dst) = *(const uint4*)sA;
        }
        *(uint4*)(lds + 32768 + dst) =
            *(const uint4*)(Wb + (size_t)(bcol + row) * 256 + (c & 31) * 8);
    }
    __syncthreads();

    const int wave = t >> 6, lane = t & 63;
    const int lrow = lane & 15, lk = lane >> 4;
    const int arow = wave * 16 + lrow;

    short8 af[8];
    #pragma unroll
    for (int ks = 0; ks < 8; ++ks) {
        int kbyte = ks * 64 + lk * 16;
        af[ks] = *(const short8*)(lds + arow * 512 + (kbyte ^ ((arow & 7) << 4)));
    }

    f32x4 acc[CT2][4] = {};
    #pragma unroll
    for (int c2 = 0; c2 < CT2; ++c2) {
        if (c2) {
            __syncthreads();
            #pragma unroll
            for (int p = 0; p < 8; ++p) {
                int c = t + p * 256;
                int row = c >> 5;
                int colb = (c & 31) * 16;
                int dst = 32768 + row * 512 + (colb ^ ((row & 7) << 4));
                *(uint4*)(lds + dst) =
                    *(const uint4*)(Wb + (size_t)(bcol + c2 * 64 + row) * 256 + (c & 31) * 8);
            }
            __syncthreads();
        }
        #pragma unroll
        for (int ks = 0; ks < 8; ++ks) {
            int kbyte = ks * 64 + lk * 16;
            #pragma unroll
            for (int ct = 0; ct < 4; ++ct) {
                int wrow = ct * 16 + lrow;
                short8 bf = *(const short8*)(lds + 32768 + wrow * 512 + (kbyte ^ ((wrow & 7) << 4)));
                acc[c2][ct] = __builtin_amdgcn_mfma_f32_16x16x32_bf16(af[ks], bf, acc[c2][ct], 0, 0, 0);
            }
        }
    }

    #pragma unroll
    for (int c2 = 0; c2 < CT2; ++c2) {
        #pragma unroll
        for (int ct = 0; ct < 4; ++ct) {
            int col = bcol + c2 * 64 + ct * 16 + lrow;
            float bv = bias[col];
            float s = 0.f, q = 0.f;
            #pragma unroll
            for (int r = 0; r < 4; ++r) {
                int grow = brow + wave * 16 + lk * 4 + r;
                float v = acc[c2][ct][r] + bv;
                if (RELU) v = fmaxf(v, 0.0f);
                if (CF32) ((float*)C)[(size_t)grow * M + col] = v;
                else      ((u16*)C)[(size_t)grow * M + col] = f2bf(v);
                if (BNSTAT) { s += v; q += v * v; }
            }
            if (BNSTAT) {
                s += __shfl_xor(s, 16); s += __shfl_xor(s, 32);
                q += __shfl_xor(q, 16); q += __shfl_xor(q, 32);
                if (lk == 0) {
                    atomicAdd(&stats[col], s);
                    atomicAdd(&stats[DD + col], q);
                }
            }
        }
    }
}

// K-chunked 16x256x256 GEMM step for the tail kernel
#define TAIL_GEMM(WPTR, LOADA)                                                            \
    _Pragma("unroll")                                                                     \
    for (int kc = 0; kc < 4; ++kc) {                                                      \
        __syncthreads();                                                                  \
        _Pragma("unroll")                                                                 \
        for (int p = 0; p < 8; ++p) {                                                     \
            int c = t + p * 256;                                                          \
            int row = c >> 3, sub = c & 7;                                                \
            *(uint4*)(Wl + row * 128 + ((sub * 16) ^ ((row & 7) << 4))) =                 \
                *(const uint4*)((WPTR) + (size_t)row * 256 + kc * 64 + sub * 8);          \
        }                                                                                 \
        __syncthreads();                                                                  \
        if ((LOADA) && kc == 0) {                                                         \
            _Pragma("unroll")                                                             \
            for (int ks = 0; ks < 8; ++ks) {                                              \
                int kbyte = ks * 64 + lk * 16;                                            \
                af[ks] = *(const short8*)(Al + lrow * 512 + (kbyte ^ ((lrow & 7) << 4))); \
            }                                                                             \
        }                                                                                 \
        _Pragma("unroll")                                                                 \
        for (int s = 0; s < 2; ++s) {                                                     \
            int kb = s * 64 + lk * 16;                                                    \
            _Pragma("unroll")                                                             \
            for (int ct = 0; ct < 4; ++ct) {                                              \
                int wrow = wcol + ct * 16 + lrow;                                         \
                short8 bf = *(const short8*)(Wl + wrow * 128 + (kb ^ ((wrow & 7) << 4))); \
                acc[ct] = __builtin_amdgcn_mfma_f32_16x16x32_bf16(af[kc * 2 + s], bf,     \
                                                                  acc[ct], 0, 0, 0);      \
            }                                                                             \
        }                                                                                 \
    }

#define WRITE_AL(VARR)                                                                    \
    _Pragma("unroll")                                                                     \
    for (int ct = 0; ct < 4; ++ct) {                                                      \
        _Pragma("unroll")                                                                 \
        for (int r = 0; r < 4; ++r) {                                                     \
            int row = lk * 4 + r, col = wcol + ct * 16 + lrow;                            \
            *(u16*)(Al + row * 512 + ((col * 2) ^ ((row & 7) << 4))) = f2bf(VARR[ct][r]); \
        }                                                                                 \
    }

#define ROW_LN_STATS(S4, Q4, MU, IV)                                                      \
    _Pragma("unroll")                                                                     \
    for (int off = 1; off < 16; off <<= 1) {                                              \
        _Pragma("unroll")                                                                 \
        for (int r = 0; r < 4; ++r) {                                                     \
            S4[r] += __shfl_xor(S4[r], off);                                              \
            Q4[r] += __shfl_xor(Q4[r], off);                                              \
        }                                                                                 \
    }                                                                                     \
    if (lrow == 0) {                                                                      \
        _Pragma("unroll")                                                                 \
        for (int r = 0; r < 4; ++r) {                                                     \
            reds[wave][lk * 4 + r] = S4[r];                                               \
            redq[wave][lk * 4 + r] = Q4[r];                                               \
        }                                                                                 \
    }                                                                                     \
    __syncthreads();                                                                      \
    _Pragma("unroll")                                                                     \
    for (int r = 0; r < 4; ++r) {                                                         \
        int rr = lk * 4 + r;                                                              \
        float S = reds[0][rr] + reds[1][rr] + reds[2][rr] + reds[3][rr];                  \
        float Q = redq[0][rr] + redq[1][rr] + redq[2][rr] + redq[3][rr];                  \
        MU[r] = S * (1.0f / DD);                                                          \
        IV[r] = rsqrtf(Q * (1.0f / DD) - MU[r] * MU[r] + 1e-5f);                          \
    }

// ---------------- fused layer tail ----------------
template <int LAST>
__global__ __launch_bounds__(256)
void aml_tail_k(const u16* __restrict__ A, float* __restrict__ h2,
                const u16* __restrict__ Wout, const float* __restrict__ bout,
                const float* __restrict__ g1, const float* __restrict__ b1,
                const u16* __restrict__ Wff1, const float* __restrict__ bff1,
                const u16* __restrict__ Wff2, const float* __restrict__ bff2,
                const float* __restrict__ g2, const float* __restrict__ b2,
                const u16* __restrict__ Wq, const float* __restrict__ bq,
                u16* __restrict__ qkv,
                const float* __restrict__ cls_w, const float* __restrict__ cls_b,
                float* __restrict__ out) {
    __shared__ __align__(16) unsigned char Al[8192];
    __shared__ __align__(16) unsigned char Wl[32768];
    __shared__ float reds[4][16], redq[4][16];
    __shared__ float redc[2][4][16];
    const int t = threadIdx.x;
    const int brow = blockIdx.x * 16;
    const int wave = t >> 6, lane = t & 63;
    const int lrow = lane & 15, lk = lane >> 4;
    const int wcol = wave * 64;

    #pragma unroll
    for (int p = 0; p < 2; ++p) {
        int c = t + p * 256;
        int row = c >> 5, c8 = c & 31;
        *(uint4*)(Al + row * 512 + ((c8 * 16) ^ ((row & 7) << 4))) =
            *(const uint4*)(A + (size_t)(brow + row) * 256 + c8 * 8);
    }

    short8 af[8];
    f32x4 acc[4];

    #pragma unroll
    for (int ct = 0; ct < 4; ++ct) acc[ct] = (f32x4){0.f, 0.f, 0.f, 0.f};
    TAIL_GEMM(Wout, true)

    float ln1v[4][4];
    {
        float s4[4] = {}, q4[4] = {};
        #pragma unroll
        for (int ct = 0; ct < 4; ++ct) {
            int col = wcol + ct * 16 + lrow;
            float bvv = bout[col];
            #pragma unroll
            for (int r = 0; r < 4; ++r) {
                int grow = brow + lk * 4 + r;
                float v = acc[ct][r] + bvv + h2[(size_t)grow * DD + col];
                acc[ct][r] = v;
                s4[r] += v; q4[r] += v * v;
            }
        }
        float mu[4], iv[4];
        ROW_LN_STATS(s4, q4, mu, iv)
        #pragma unroll
        for (int ct = 0; ct < 4; ++ct) {
            int col = wcol + ct * 16 + lrow;
            float gv = g1[col], bb = b1[col];
            #pragma unroll
            for (int r = 0; r < 4; ++r)
                ln1v[ct][r] = (acc[ct][r] - mu[r]) * iv[r] * gv + bb;
        }
        WRITE_AL(ln1v)
    }

    #pragma unroll
    for (int ct = 0; ct < 4; ++ct) acc[ct] = (f32x4){0.f, 0.f, 0.f, 0.f};
    TAIL_GEMM(Wff1, true)
    {
        float fv[4][4];
        #pragma unroll
        for (int ct = 0; ct < 4; ++ct) {
            int col = wcol + ct * 16 + lrow;
            float bvv = bff1[col];
            #pragma unroll
            for (int r = 0; r < 4; ++r)
                fv[ct][r] = fmaxf(acc[ct][r] + bvv, 0.0f);
        }
        __syncthreads();
        WRITE_AL(fv)
    }

    #pragma unroll
    for (int ct = 0; ct < 4; ++ct) acc[ct] = (f32x4){0.f, 0.f, 0.f, 0.f};
    TAIL_GEMM(Wff2, true)
    float ln2v[4][4];
    {
        float s4[4] = {}, q4[4] = {};
        #pragma unroll
        for (int ct = 0; ct < 4; ++ct) {
            int col = wcol + ct * 16 + lrow;
            float bvv = bff2[col];
            #pragma unroll
            for (int r = 0; r < 4; ++r) {
                float v = acc[ct][r] + bvv + ln1v[ct][r];
                acc[ct][r] = v;
                s4[r] += v; q4[r] += v * v;
            }
        }
        float mu[4], iv[4];
        ROW_LN_STATS(s4, q4, mu, iv)
        #pragma unroll
        for (int ct = 0; ct < 4; ++ct) {
            int col = wcol + ct * 16 + lrow;
            float gv = g2[col], bb = b2[col];
            #pragma unroll
            for (int r = 0; r < 4; ++r) {
                float v = (acc[ct][r] - mu[r]) * iv[r] * gv + bb;
                ln2v[ct][r] = v;
                if (!LAST) {
                    int grow = brow + lk * 4 + r;
                    h2[(size_t)grow * DD + col] = v;
                }
            }
        }
        if (!LAST) {
            WRITE_AL(ln2v)
        }
    }

    if (!LAST) {
        #pragma unroll
        for (int cg = 0; cg < 3; ++cg) {
            #pragma unroll
            for (int ct = 0; ct < 4; ++ct) acc[ct] = (f32x4){0.f, 0.f, 0.f, 0.f};
            TAIL_GEMM(Wq + (size_t)cg * 256 * 256, cg == 0)
            #pragma unroll
            for (int ct = 0; ct < 4; ++ct) {
                int col = cg * 256 + wcol + ct * 16 + lrow;
                float bvv = bq[col];
                #pragma unroll
                for (int r = 0; r < 4; ++r) {
                    int grow = brow + lk * 4 + r;
                    qkv[(size_t)grow * 768 + col] = f2bf(acc[ct][r] + bvv);
                }
            }
        }
    } else {
        float c0[4] = {}, c1[4] = {};
        #pragma unroll
        for (int ct = 0; ct < 4; ++ct) {
            int col = wcol + ct * 16 + lrow;
            float w0 = cls_w[col], w1 = cls_w[DD + col];
            #pragma unroll
            for (int r = 0; r < 4; ++r) {
                c0[r] += ln2v[ct][r] * w0;
                c1[r] += ln2v[ct][r] * w1;
            }
        }
        #pragma unroll
        for (int off = 1; off < 16; off <<= 1) {
            #pragma unroll
            for (int r = 0; r < 4; ++r) {
                c0[r] += __shfl_xor(c0[r], off);
                c1[r] += __shfl_xor(c1[r], off);
            }
        }
        if (lrow == 0) {
            #pragma unroll
            for (int r = 0; r < 4; ++r) {
                redc[0][wave][lk * 4 + r] = c0[r];
                redc[1][wave][lk * 4 + r] = c1[r];
            }
        }
        __syncthreads();
        if (wave == 0 && lrow == 0) {
            float cb0 = cls_b[0], cb1 = cls_b[1];
            #pragma unroll
            for (int r = 0; r < 4; ++r) {
                int rr = lk * 4 + r;
                float o0 = redc[0][0][rr] + redc[0][1][rr] + redc[0][2][rr] + redc[0][3][rr];
                float o1 = redc[1][0][rr] + redc[1][1][rr] + redc[1][2][rr] + redc[1][3][rr];
                out[(brow + rr) * 2]     = o0 + cb0;
                out[(brow + rr) * 2 + 1] = o1 + cb1;
            }
        }
    }
}

// ---------------- split-K MFMA attention: one 64q x 64k tile per block ----------------
// grid (TT, NH, ZQ*ZK). Writes unnormalized partial O (f32) + per-q m,l.
__global__ __launch_bounds__(256)
void aml_attn_k(const u16* __restrict__ qkv, const int* __restrict__ offs,
                float* __restrict__ Opart, float* __restrict__ mpart,
                float* __restrict__ lpart) {
    int tb = blockIdx.x, head = blockIdx.y;
    int zq = blockIdx.z / ZK, zk = blockIdx.z % ZK;
    int start = offs[tb], end = offs[tb + 1];
    int S = end - start;
    if (S <= zq * 64 || zk * 64 >= S) return;
    int t = threadIdx.x, wave = t >> 6, lane = t & 63;
    int lq = lane & 15, lk = lane >> 4;
    int qoff = head * 64;

    __shared__ __align__(16) unsigned char Kl[8192];
    __shared__ __align__(16) unsigned char Vt[8192];
    __shared__ __align__(16) unsigned char Pl[4][2048];
    __shared__ float Ol[4][16][65];

    int qi = start + zq * 64 + wave * 16 + lq;
    int qic = min(qi, end - 1);
    const u16* qp = qkv + (size_t)qic * 768 + qoff + lk * 8;
    short8 qf[2];
    qf[0] = *(const short8*)qp;
    qf[1] = *(const short8*)(qp + 32);

    int jcnt = S - zk * 64; if (jcnt > 64) jcnt = 64;
    // ---- K staging ----
    {
        int j = t >> 2, d0 = (t & 3) * 16;
        unsigned char* krow = Kl + j * 128;
        if (j < jcnt) {
            const u16* kp = qkv + (size_t)(start + zk * 64 + j) * 768 + 256 + qoff + d0;
            *(uint4*)(krow + ((d0 * 2) ^ ((j & 7) << 4))) = *(const uint4*)kp;
            *(uint4*)(krow + ((d0 * 2 + 16) ^ ((j & 7) << 4))) = *(const uint4*)(kp + 8);
        } else {
            uint4 zz = { 0, 0, 0, 0 };
            *(uint4*)(krow + ((d0 * 2) ^ ((j & 7) << 4))) = zz;
            *(uint4*)(krow + ((d0 * 2 + 16) ^ ((j & 7) << 4))) = zz;
        }
    }
    // ---- V staging transposed (paired) ----
    {
        int j0 = (t & 31) * 2, d0v = (t >> 5) * 8;
        const u16* vbase = qkv + (size_t)(start + zk * 64) * 768 + 512 + qoff + d0v;
        uint4 va = { 0, 0, 0, 0 }, vb = { 0, 0, 0, 0 };
        if (j0 < jcnt)     va = *(const uint4*)(vbase + (size_t)j0 * 768);
        if (j0 + 1 < jcnt) vb = *(const uint4*)(vbase + (size_t)(j0 + 1) * 768);
        const u16* pa = (const u16*)&va;
        const u16* pb = (const u16*)&vb;
        #pragma unroll
        for (int i = 0; i < 8; ++i) {
            int d = d0v + i;
            unsigned w = (unsigned)pa[i] | ((unsigned)pb[i] << 16);
            *(unsigned*)(Vt + d * 128 + ((j0 * 2) ^ ((d & 7) << 4))) = w;
        }
    }
    __syncthreads();

    // ---- S^T = K·Q ----
    f32x4 sv[4];
    #pragma unroll
    for (int kt = 0; kt < 4; ++kt) {
        int kr = kt * 16 + lq;
        f32x4 s = {};
        #pragma unroll
        for (int ks = 0; ks < 2; ++ks) {
            short8 kf = *(const short8*)(Kl + kr * 128 + ((ks * 64 + lk * 16) ^ ((kr & 7) << 4)));
            s = __builtin_amdgcn_mfma_f32_16x16x32_bf16(kf, qf[ks], s, 0, 0, 0);
        }
        sv[kt] = s;
    }
    // ---- local softmax (per q = lane&15) ----
    float pm = -1e30f;
    #pragma unroll
    for (int kt = 0; kt < 4; ++kt) {
        #pragma unroll
        for (int r = 0; r < 4; ++r) {
            int kk = zk * 64 + kt * 16 + lk * 4 + r;
            float s = (kk < S) ? sv[kt][r] * 0.125f : -1e30f;
            sv[kt][r] = s;
            pm = fmaxf(pm, s);
        }
    }
    pm = fmaxf(pm, __shfl_xor(pm, 16));
    pm = fmaxf(pm, __shfl_xor(pm, 32));
    float ps = 0.f;
    #pragma unroll
    for (int kt = 0; kt < 4; ++kt) {
        #pragma unroll
        for (int r = 0; r < 4; ++r) {
            float p = __expf(sv[kt][r] - pm);
            sv[kt][r] = p;
            ps += p;
        }
        uint2 w = { pk2(sv[kt][0], sv[kt][1]), pk2(sv[kt][2], sv[kt][3]) };
        *(uint2*)(Pl[wave] + lq * 128 + ((kt * 32 + lk * 8) ^ ((lq & 7) << 4))) = w;
    }
    ps += __shfl_xor(ps, 16);
    ps += __shfl_xor(ps, 32);
    // store m,l (one lane per q)
    if (lk == 0 && qi < end) {
        mpart[((size_t)zk * NN + qi) * NH + head] = pm;
        lpart[((size_t)zk * NN + qi) * NH + head] = ps;
    }
    // ---- O_part = P·V (unnormalized) ----
    f32x4 acc[4] = {};
    #pragma unroll
    for (int ks = 0; ks < 2; ++ks) {
        short8 pf = *(const short8*)(Pl[wave] + lq * 128 + ((ks * 64 + lk * 16) ^ ((lq & 7) << 4)));
        #pragma unroll
        for (int dt = 0; dt < 4; ++dt) {
            int dr = dt * 16 + lq;
            short8 vf = *(const short8*)(Vt + dr * 128 + ((ks * 64 + lk * 16) ^ ((dr & 7) << 4)));
            acc[dt] = __builtin_amdgcn_mfma_f32_16x16x32_bf16(vf, pf, acc[dt], 0, 0, 0);
        }
    }

    // ---- transpose through Ol, store f32 partial ----
    #pragma unroll
    for (int dt = 0; dt < 4; ++dt) {
        #pragma unroll
        for (int r = 0; r < 4; ++r)
            Ol[wave][lq][dt * 16 + lk * 4 + r] = acc[dt][r];
    }
    int q2 = lane >> 2, c2 = lane & 3;
    int qg = start + zq * 64 + wave * 16 + q2;
    if (qg < end) {
        float* op = Opart + ((size_t)zk * NN + qg) * DD + qoff + c2 * 16;
        const float* sp = &Ol[wave][q2][c2 * 16];
        #pragma unroll
        for (int i = 0; i < 4; ++i) ((float4*)op)[i] = *(const float4*)(sp + i * 4);
    }
}

// ---------------- combine partials -> bf16 attention output ----------------
__global__ __launch_bounds__(256)
void aml_comb_k(const float* __restrict__ Opart, const float* __restrict__ mpart,
                const float* __restrict__ lpart, const int* __restrict__ ts,
                const int* __restrict__ offs, u16* __restrict__ o) {
    int t = threadIdx.x, head = t >> 6, lane = t & 63;
    int lq = lane & 15, ld = lane >> 4;
    int q = blockIdx.x * 16 + lq;
    int tb = ts[q];
    int S = offs[tb + 1] - offs[tb];
    int ntile = (S + 63) >> 6;

    float M = -1e30f;
    for (int i = 0; i < ntile; ++i)
        M = fmaxf(M, mpart[((size_t)i * NN + q) * NH + head]);
    float L = 0.f;
    float ov[16] = {};
    for (int i = 0; i < ntile; ++i) {
        float w = __expf(mpart[((size_t)i * NN + q) * NH + head] - M);
        L += lpart[((size_t)i * NN + q) * NH + head] * w;
        const float* op = Opart + ((size_t)i * NN + q) * DD + head * 64 + ld * 16;
        #pragma unroll
        for (int j = 0; j < 16; j += 4) {
            float4 v = *(const float4*)(op + j);
            ov[j] += v.x * w; ov[j + 1] += v.y * w;
            ov[j + 2] += v.z * w; ov[j + 3] += v.w * w;
        }
    }
    float linv = 1.0f / L;
    u16* dst = o + (size_t)q * DD + head * 64 + ld * 16;
    #pragma unroll
    for (int j = 0; j < 8; ++j)
        ((unsigned*)dst)[j] = pk2(ov[2 * j] * linv, ov[2 * j + 1] * linv);
}

extern "C" void kernel_launch(void* const* d_in, const int* in_sizes, int n_in,
                              void* d_out, int out_size, void* d_ws, size_t ws_size,
                              hipStream_t stream) {
    const float* x       = (const float*)d_in[0];
    const int*   ei      = (const int*)d_in[1];
    const int*   ts      = (const int*)d_in[2];
    const float* lin_l_w = (const float*)d_in[3];
    const float* lin_l_b = (const float*)d_in[4];
    const float* lin_r_w = (const float*)d_in[5];
    const float* bn_g    = (const float*)d_in[6];
    const float* bn_b    = (const float*)d_in[7];
    const float* inp_w   = (const float*)d_in[8];
    const float* inp_b   = (const float*)d_in[9];
    const float* out_w   = (const float*)d_in[10];
    const float* out_b   = (const float*)d_in[11];
    const float* ff1_w   = (const float*)d_in[12];
    const float* ff1_b   = (const float*)d_in[13];
    const float* ff2_w   = (const float*)d_in[14];
    const float* ff2_b   = (const float*)d_in[15];
    const float* ln1_g   = (const float*)d_in[16];
    const float* ln1_b   = (const float*)d_in[17];
    const float* ln2_g   = (const float*)d_in[18];
    const float* ln2_b   = (const float*)d_in[19];
    const float* cls_w   = (const float*)d_in[20];
    const float* cls_b   = (const float*)d_in[21];

    float* ws     = (float*)d_ws;
    float* stats  = ws;
    int*   deg    = (int*)(stats + 512);
    int*   rowptr = deg + NN;
    int*   cursor = rowptr + NN + 4;
    int*   eid    = cursor + NN;
    int*   offs   = eid + EE;
    u16*   wb     = (u16*)(offs + 64);
    u16*   hb     = wb + (size_t)WROWS * 256;
    float* h2     = (float*)(hb + (size_t)NN * DD);
    u16*   qkv    = (u16*)(h2 + (size_t)NN * DD);
    u16*   t1     = qkv + (size_t)NN * 768;
    float* Opart  = (float*)(t1 + (size_t)NN * DD);     // ZK*NN*256 f32
    float* mpart  = Opart + (size_t)ZK * NN * DD;       // ZK*NN*NH f32
    float* lpart  = mpart + (size_t)ZK * NN * NH;       // ZK*NN*NH f32
    u16*   ac     = qkv;

    const u16* wb_cat = wb;
    const u16* wb_inp[2] = { wb + (size_t)(256) * 256,        wb + (size_t)(256 + 1536) * 256 };
    const u16* wb_out[2] = { wb + (size_t)(256 + 768) * 256,  wb + (size_t)(256 + 1536 + 768) * 256 };
    const u16* wb_ff1[2] = { wb + (size_t)(256 + 1024) * 256, wb + (size_t)(256 + 1536 + 1024) * 256 };
    const u16* wb_ff2[2] = { wb + (size_t)(256 + 1280) * 256, wb + (size_t)(256 + 1536 + 1280) * 256 };

    aml_prep_k<<<WROWS + 27, 256, 0, stream>>>(lin_l_w, lin_r_w, inp_w, out_w, ff1_w, ff2_w,
                                               ts, wb, offs, stats);
    aml_hist_k<<<EE / 256, 256, 0, stream>>>(ei, deg);
    aml_scan_k<<<1, 256, 0, stream>>>(deg, rowptr, cursor);
    aml_scatter2_k<<<EE / 256, 256, 0, stream>>>(ei, cursor, eid);
    aml_gather_k<<<NN / 4, 256, 0, stream>>>(x, rowptr, eid, ac);
    aml_gemm_k<0, 0, 0, 1, 1><<<dim3(NN / 64, 4), 256, 0, stream>>>(
        ac, wb_cat, lin_l_b, hb, DD, stats, nullptr, nullptr, nullptr);
    aml_gemm_k<0, 2, 0, 0, 1><<<dim3(NN / 64, 12), 256, 0, stream>>>(
        hb, wb_inp[0], inp_b, qkv, 768, stats, bn_g, bn_b, h2);

    // layer 0
    aml_attn_k<<<dim3(TT, NH, ZQ * ZK), 256, 0, stream>>>(qkv, offs, Opart, mpart, lpart);
    aml_comb_k<<<NN / 16, 256, 0, stream>>>(Opart, mpart, lpart, ts, offs, t1);
    aml_tail_k<0><<<NN / 16, 256, 0, stream>>>(
        t1, h2, wb_out[0], out_b, ln1_g, ln1_b,
        wb_ff1[0], ff1_b, wb_ff2[0], ff2_b, ln2_g, ln2_b,
        wb_inp[1], inp_b + 768, qkv, nullptr, nullptr, nullptr);

    // layer 1
    aml_attn_k<<<dim3(TT, NH, ZQ * ZK), 256, 0, stream>>>(qkv, offs, Opart, mpart, lpart);
    aml_comb_k<<<NN / 16, 256, 0, stream>>>(Opart, mpart, lpart, ts, offs, t1);
    aml_tail_k<1><<<NN / 16, 256, 0, stream>>>(
        t1, h2, wb_out[1], out_b + DD, ln1_g + DD, ln1_b + DD,
        wb_ff1[1], ff1_b + DD, wb_ff2[1], ff2_b + DD, ln2_g + DD, ln2_b + DD,
        nullptr, nullptr, nullptr, cls_w, cls_b, (float*)d_out);
}

// Round 19
// 153.517 us; speedup vs baseline: 1.1795x; 1.1795x over previous
//
#include <hip/hip_runtime.h>

#define NN   6144
#define EE   98304
#define DIN  128
#define DD   256
#define TT   32
#define NH   4
#define ATTN_Z 6
#define WROWS 3328

typedef __attribute__((ext_vector_type(8))) short short8;
typedef __attribute__((ext_vector_type(4))) float f32x4;
typedef unsigned short u16;

__device__ __forceinline__ float bf2f(u16 u) {
    return __uint_as_float(((unsigned)u) << 16);
}
__device__ __forceinline__ u16 f2bf(float f) {
    unsigned u = __float_as_uint(f);
    return (u16)((u + 0x7fffu + ((u >> 16) & 1u)) >> 16);
}
__device__ __forceinline__ unsigned pk2(float a, float b) {
    return (unsigned)f2bf(a) | ((unsigned)f2bf(b) << 16);
}
__device__ __forceinline__ float bnrelu(float v, float s, float q, float g, float b) {
    float mu = s * (1.0f / NN);
    float var = q * (1.0f / NN) - mu * mu;
    return fmaxf((v - mu) * rsqrtf(var + 1e-5f) * g + b, 0.0f);
}

// ---------------- CSR build ----------------
__global__ void aml_hist_k(const int* __restrict__ ei, int* __restrict__ deg) {
    int e = blockIdx.x * 256 + threadIdx.x;
    if (e < EE) atomicAdd(&deg[ei[EE + e]], 1);
}

__global__ void aml_scan_k(const int* __restrict__ deg, int* __restrict__ rowptr,
                           int* __restrict__ cursor) {
    int t = threadIdx.x;
    int base = t * 24;
    int loc[24];
    int s = 0;
    #pragma unroll
    for (int j = 0; j < 24; ++j) { loc[j] = s; s += deg[base + j]; }
    __shared__ int part[256];
    part[t] = s;
    __syncthreads();
    for (int o = 1; o < 256; o <<= 1) {
        int v = (t >= o) ? part[t - o] : 0;
        __syncthreads();
        part[t] += v;
        __syncthreads();
    }
    int off = (t > 0) ? part[t - 1] : 0;
    #pragma unroll
    for (int j = 0; j < 24; ++j) {
        rowptr[base + j] = off + loc[j];
        cursor[base + j] = off + loc[j];
    }
    if (t == 255) rowptr[NN] = part[255];
}

__global__ void aml_scatter2_k(const int* __restrict__ ei, int* __restrict__ cursor,
                               int* __restrict__ eid) {
    int e = blockIdx.x * 256 + threadIdx.x;
    if (e >= EE) return;
    int slot = atomicAdd(&cursor[ei[EE + e]], 1);
    eid[slot] = ei[e];
}

__global__ void aml_gather_k(const float* __restrict__ x, const int* __restrict__ rowptr,
                             const int* __restrict__ eid, u16* __restrict__ ac) {
    int node = blockIdx.x * 4 + (threadIdx.x >> 6);
    int lane = threadIdx.x & 63;
    int p0 = rowptr[node], p1 = rowptr[node + 1];
    float ax = 0.f, ay = 0.f;
    int j = p0;
    for (; j + 1 < p1; j += 2) {
        int s0 = eid[j], s1 = eid[j + 1];
        float2 v0 = *(const float2*)(x + (size_t)s0 * DIN + lane * 2);
        float2 v1 = *(const float2*)(x + (size_t)s1 * DIN + lane * 2);
        ax += v0.x + v1.x; ay += v0.y + v1.y;
    }
    if (j < p1) {
        float2 v = *(const float2*)(x + (size_t)eid[j] * DIN + lane * 2);
        ax += v.x; ay += v.y;
    }
    float inv = 1.0f / fmaxf((float)(p1 - p0), 1.0f);
    float2 xr = *(const float2*)(x + (size_t)node * DIN + lane * 2);
    *(unsigned*)(ac + (size_t)node * DD + lane * 2) = pk2(ax * inv, ay * inv);
    *(unsigned*)(ac + (size_t)node * DD + DIN + lane * 2) = pk2(xr.x, xr.y);
}

// ---------------- prep weights + segment offsets + zero stats/deg ----------------
__global__ void aml_prep_k(const float* __restrict__ lin_l_w, const float* __restrict__ lin_r_w,
                           const float* __restrict__ inp_w, const float* __restrict__ out_w,
                           const float* __restrict__ ff1_w, const float* __restrict__ ff2_w,
                           const int* __restrict__ ts, u16* __restrict__ wb,
                           int* __restrict__ offs, float* __restrict__ zero_region) {
    int r = blockIdx.x;
    if (r > WROWS) {
        zero_region[(r - WROWS - 1) * 256 + threadIdx.x] = 0.0f;
        return;
    }
    if (r == WROWS) {
        int t = threadIdx.x;
        if (t <= TT) {
            int lo = 0, hi = NN;
            while (lo < hi) { int mid = (lo + hi) >> 1; if (ts[mid] < t) lo = mid + 1; else hi = mid; }
            offs[t] = lo;
        }
        return;
    }
    int k = threadIdx.x;
    float v;
    if (r < 256) {
        v = (k < DIN) ? lin_l_w[r * DIN + k] : lin_r_w[r * DIN + (k - DIN)];
    } else {
        int r2 = r - 256;
        int l = r2 / 1536, r3 = r2 % 1536;
        const float* src; int rr;
        if (r3 < 768)       { src = inp_w + (size_t)l * 768 * DD; rr = r3; }
        else if (r3 < 1024) { src = out_w + (size_t)l * DD * DD;  rr = r3 - 768; }
        else if (r3 < 1280) { src = ff1_w + (size_t)l * DD * DD;  rr = r3 - 1024; }
        else                { src = ff2_w + (size_t)l * DD * DD;  rr = r3 - 1280; }
        v = src[(size_t)rr * DD + k];
    }
    wb[(size_t)r * DD + k] = f2bf(v);
}

// ---------------- MFMA GEMM (sage / qkv0), CT2=1 for occupancy ----------------
template <int RELU, int AMODE, int CF32, int BNSTAT, int CT2>
__global__ __launch_bounds__(256)
void aml_gemm_k(const void* __restrict__ A, const u16* __restrict__ Wb,
                const float* __restrict__ bias, void* __restrict__ C, int M,
                float* __restrict__ stats, const float* __restrict__ bng,
                const float* __restrict__ bnb, float* __restrict__ h2) {
    __shared__ __align__(16) unsigned char lds[65536];
    const int t = threadIdx.x;
    const int brow = blockIdx.x * 64;
    const int bcol = blockIdx.y * (64 * CT2);

    #pragma unroll
    for (int p = 0; p < 8; ++p) {
        int c = t + p * 256;
        int row = c >> 5;
        int colb = (c & 31) * 16;
        int dst = row * 512 + (colb ^ ((row & 7) << 4));
        if (AMODE == 2) {
            int d0 = (c & 31) * 8;
            const u16* sA = (const u16*)A + (size_t)(brow + row) * 256 + d0;
            uint4 raw = *(const uint4*)sA;
            const u16* rp = (const u16*)&raw;
            float av[8];
            #pragma unroll
            for (int i = 0; i < 8; ++i) {
                int d = d0 + i;
                av[i] = bnrelu(bf2f(rp[i]), stats[d], stats[DD + d], bng[d], bnb[d]);
            }
            if (blockIdx.y == 0) {
                float* hp = h2 + (size_t)(brow + row) * 256 + d0;
                *(float4*)hp = make_float4(av[0], av[1], av[2], av[3]);
                *(float4*)(hp + 4) = make_float4(av[4], av[5], av[6], av[7]);
            }
            uint4 pa = { pk2(av[0], av[1]), pk2(av[2], av[3]), pk2(av[4], av[5]), pk2(av[6], av[7]) };
            *(uint4*)(lds + dst) = pa;
        } else {
            const u16* sA = (const u16*)A + (size_t)(brow + row) * 256 + (c & 31) * 8;
            *(uint4*)(lds + dst) = *(const uint4*)sA;
        }
        *(uint4*)(lds + 32768 + dst) =
            *(const uint4*)(Wb + (size_t)(bcol + row) * 256 + (c & 31) * 8);
    }
    __syncthreads();

    const int wave = t >> 6, lane = t & 63;
    const int lrow = lane & 15, lk = lane >> 4;
    const int arow = wave * 16 + lrow;

    short8 af[8];
    #pragma unroll
    for (int ks = 0; ks < 8; ++ks) {
        int kbyte = ks * 64 + lk * 16;
        af[ks] = *(const short8*)(lds + arow * 512 + (kbyte ^ ((arow & 7) << 4)));
    }

    f32x4 acc[CT2][4] = {};
    #pragma unroll
    for (int c2 = 0; c2 < CT2; ++c2) {
        if (c2) {
            __syncthreads();
            #pragma unroll
            for (int p = 0; p < 8; ++p) {
                int c = t + p * 256;
                int row = c >> 5;
                int colb = (c & 31) * 16;
                int dst = 32768 + row * 512 + (colb ^ ((row & 7) << 4));
                *(uint4*)(lds + dst) =
                    *(const uint4*)(Wb + (size_t)(bcol + c2 * 64 + row) * 256 + (c & 31) * 8);
            }
            __syncthreads();
        }
        #pragma unroll
        for (int ks = 0; ks < 8; ++ks) {
            int kbyte = ks * 64 + lk * 16;
            #pragma unroll
            for (int ct = 0; ct < 4; ++ct) {
                int wrow = ct * 16 + lrow;
                short8 bf = *(const short8*)(lds + 32768 + wrow * 512 + (kbyte ^ ((wrow & 7) << 4)));
                acc[c2][ct] = __builtin_amdgcn_mfma_f32_16x16x32_bf16(af[ks], bf, acc[c2][ct], 0, 0, 0);
            }
        }
    }

    #pragma unroll
    for (int c2 = 0; c2 < CT2; ++c2) {
        #pragma unroll
        for (int ct = 0; ct < 4; ++ct) {
            int col = bcol + c2 * 64 + ct * 16 + lrow;
            float bv = bias[col];
            float s = 0.f, q = 0.f;
            #pragma unroll
            for (int r = 0; r < 4; ++r) {
                int grow = brow + wave * 16 + lk * 4 + r;
                float v = acc[c2][ct][r] + bv;
                if (RELU) v = fmaxf(v, 0.0f);
                if (CF32) ((float*)C)[(size_t)grow * M + col] = v;
                else      ((u16*)C)[(size_t)grow * M + col] = f2bf(v);
                if (BNSTAT) { s += v; q += v * v; }
            }
            if (BNSTAT) {
                s += __shfl_xor(s, 16); s += __shfl_xor(s, 32);
                q += __shfl_xor(q, 16); q += __shfl_xor(q, 32);
                if (lk == 0) {
                    atomicAdd(&stats[col], s);
                    atomicAdd(&stats[DD + col], q);
                }
            }
        }
    }
}

// K-chunked 16x256x256 GEMM step for the tail kernel (acc[4] += Al x W^T)
#define TAIL_GEMM(WPTR, LOADA)                                                            \
    _Pragma("unroll")                                                                     \
    for (int kc = 0; kc < 4; ++kc) {                                                      \
        __syncthreads();                                                                  \
        _Pragma("unroll")                                                                 \
        for (int p = 0; p < 8; ++p) {                                                     \
            int c = t + p * 256;                                                          \
            int row = c >> 3, sub = c & 7;                                                \
            *(uint4*)(Wl + row * 128 + ((sub * 16) ^ ((row & 7) << 4))) =                 \
                *(const uint4*)((WPTR) + (size_t)row * 256 + kc * 64 + sub * 8);          \
        }                                                                                 \
        __syncthreads();                                                                  \
        if ((LOADA) && kc == 0) {                                                         \
            _Pragma("unroll")                                                             \
            for (int ks = 0; ks < 8; ++ks) {                                              \
                int kbyte = ks * 64 + lk * 16;                                            \
                af[ks] = *(const short8*)(Al + lrow * 512 + (kbyte ^ ((lrow & 7) << 4))); \
            }                                                                             \
        }                                                                                 \
        _Pragma("unroll")                                                                 \
        for (int s = 0; s < 2; ++s) {                                                     \
            int kb = s * 64 + lk * 16;                                                    \
            _Pragma("unroll")                                                             \
            for (int ct = 0; ct < 4; ++ct) {                                              \
                int wrow = wcol + ct * 16 + lrow;                                         \
                short8 bf = *(const short8*)(Wl + wrow * 128 + (kb ^ ((wrow & 7) << 4))); \
                acc[ct] = __builtin_amdgcn_mfma_f32_16x16x32_bf16(af[kc * 2 + s], bf,     \
                                                                  acc[ct], 0, 0, 0);      \
            }                                                                             \
        }                                                                                 \
    }

#define WRITE_AL(VARR)                                                                    \
    _Pragma("unroll")                                                                     \
    for (int ct = 0; ct < 4; ++ct) {                                                      \
        _Pragma("unroll")                                                                 \
        for (int r = 0; r < 4; ++r) {                                                     \
            int row = lk * 4 + r, col = wcol + ct * 16 + lrow;                            \
            *(u16*)(Al + row * 512 + ((col * 2) ^ ((row & 7) << 4))) = f2bf(VARR[ct][r]); \
        }                                                                                 \
    }

#define ROW_LN_STATS(S4, Q4, MU, IV)                                                      \
    _Pragma("unroll")                                                                     \
    for (int off = 1; off < 16; off <<= 1) {                                              \
        _Pragma("unroll")                                                                 \
        for (int r = 0; r < 4; ++r) {                                                     \
            S4[r] += __shfl_xor(S4[r], off);                                              \
            Q4[r] += __shfl_xor(Q4[r], off);                                              \
        }                                                                                 \
    }                                                                                     \
    if (lrow == 0) {                                                                      \
        _Pragma("unroll")                                                                 \
        for (int r = 0; r < 4; ++r) {                                                     \
            reds[wave][lk * 4 + r] = S4[r];                                               \
            redq[wave][lk * 4 + r] = Q4[r];                                               \
        }                                                                                 \
    }                                                                                     \
    __syncthreads();                                                                      \
    _Pragma("unroll")                                                                     \
    for (int r = 0; r < 4; ++r) {                                                         \
        int rr = lk * 4 + r;                                                              \
        float S = reds[0][rr] + reds[1][rr] + reds[2][rr] + reds[3][rr];                  \
        float Q = redq[0][rr] + redq[1][rr] + redq[2][rr] + redq[3][rr];                  \
        MU[r] = S * (1.0f / DD);                                                          \
        IV[r] = rsqrtf(Q * (1.0f / DD) - MU[r] * MU[r] + 1e-5f);                          \
    }

// ---------------- fused layer tail ----------------
template <int LAST>
__global__ __launch_bounds__(256)
void aml_tail_k(const u16* __restrict__ A, float* __restrict__ h2,
                const u16* __restrict__ Wout, const float* __restrict__ bout,
                const float* __restrict__ g1, const float* __restrict__ b1,
                const u16* __restrict__ Wff1, const float* __restrict__ bff1,
                const u16* __restrict__ Wff2, const float* __restrict__ bff2,
                const float* __restrict__ g2, const float* __restrict__ b2,
                const u16* __restrict__ Wq, const float* __restrict__ bq,
                u16* __restrict__ qkv,
                const float* __restrict__ cls_w, const float* __restrict__ cls_b,
                float* __restrict__ out) {
    __shared__ __align__(16) unsigned char Al[8192];
    __shared__ __align__(16) unsigned char Wl[32768];
    __shared__ float reds[4][16], redq[4][16];
    __shared__ float redc[2][4][16];
    const int t = threadIdx.x;
    const int brow = blockIdx.x * 16;
    const int wave = t >> 6, lane = t & 63;
    const int lrow = lane & 15, lk = lane >> 4;
    const int wcol = wave * 64;

    #pragma unroll
    for (int p = 0; p < 2; ++p) {
        int c = t + p * 256;
        int row = c >> 5, c8 = c & 31;
        *(uint4*)(Al + row * 512 + ((c8 * 16) ^ ((row & 7) << 4))) =
            *(const uint4*)(A + (size_t)(brow + row) * 256 + c8 * 8);
    }

    short8 af[8];
    f32x4 acc[4];

    #pragma unroll
    for (int ct = 0; ct < 4; ++ct) acc[ct] = (f32x4){0.f, 0.f, 0.f, 0.f};
    TAIL_GEMM(Wout, true)

    float ln1v[4][4];
    {
        float s4[4] = {}, q4[4] = {};
        #pragma unroll
        for (int ct = 0; ct < 4; ++ct) {
            int col = wcol + ct * 16 + lrow;
            float bvv = bout[col];
            #pragma unroll
            for (int r = 0; r < 4; ++r) {
                int grow = brow + lk * 4 + r;
                float v = acc[ct][r] + bvv + h2[(size_t)grow * DD + col];
                acc[ct][r] = v;
                s4[r] += v; q4[r] += v * v;
            }
        }
        float mu[4], iv[4];
        ROW_LN_STATS(s4, q4, mu, iv)
        #pragma unroll
        for (int ct = 0; ct < 4; ++ct) {
            int col = wcol + ct * 16 + lrow;
            float gv = g1[col], bb = b1[col];
            #pragma unroll
            for (int r = 0; r < 4; ++r)
                ln1v[ct][r] = (acc[ct][r] - mu[r]) * iv[r] * gv + bb;
        }
        WRITE_AL(ln1v)
    }

    #pragma unroll
    for (int ct = 0; ct < 4; ++ct) acc[ct] = (f32x4){0.f, 0.f, 0.f, 0.f};
    TAIL_GEMM(Wff1, true)
    {
        float fv[4][4];
        #pragma unroll
        for (int ct = 0; ct < 4; ++ct) {
            int col = wcol + ct * 16 + lrow;
            float bvv = bff1[col];
            #pragma unroll
            for (int r = 0; r < 4; ++r)
                fv[ct][r] = fmaxf(acc[ct][r] + bvv, 0.0f);
        }
        __syncthreads();
        WRITE_AL(fv)
    }

    #pragma unroll
    for (int ct = 0; ct < 4; ++ct) acc[ct] = (f32x4){0.f, 0.f, 0.f, 0.f};
    TAIL_GEMM(Wff2, true)
    float ln2v[4][4];
    {
        float s4[4] = {}, q4[4] = {};
        #pragma unroll
        for (int ct = 0; ct < 4; ++ct) {
            int col = wcol + ct * 16 + lrow;
            float bvv = bff2[col];
            #pragma unroll
            for (int r = 0; r < 4; ++r) {
                float v = acc[ct][r] + bvv + ln1v[ct][r];
                acc[ct][r] = v;
                s4[r] += v; q4[r] += v * v;
            }
        }
        float mu[4], iv[4];
        ROW_LN_STATS(s4, q4, mu, iv)
        #pragma unroll
        for (int ct = 0; ct < 4; ++ct) {
            int col = wcol + ct * 16 + lrow;
            float gv = g2[col], bb = b2[col];
            #pragma unroll
            for (int r = 0; r < 4; ++r) {
                float v = (acc[ct][r] - mu[r]) * iv[r] * gv + bb;
                ln2v[ct][r] = v;
                if (!LAST) {
                    int grow = brow + lk * 4 + r;
                    h2[(size_t)grow * DD + col] = v;
                }
            }
        }
        if (!LAST) {
            WRITE_AL(ln2v)
        }
    }

    if (!LAST) {
        #pragma unroll
        for (int cg = 0; cg < 3; ++cg) {
            #pragma unroll
            for (int ct = 0; ct < 4; ++ct) acc[ct] = (f32x4){0.f, 0.f, 0.f, 0.f};
            TAIL_GEMM(Wq + (size_t)cg * 256 * 256, cg == 0)
            #pragma unroll
            for (int ct = 0; ct < 4; ++ct) {
                int col = cg * 256 + wcol + ct * 16 + lrow;
                float bvv = bq[col];
                #pragma unroll
                for (int r = 0; r < 4; ++r) {
                    int grow = brow + lk * 4 + r;
                    qkv[(size_t)grow * 768 + col] = f2bf(acc[ct][r] + bvv);
                }
            }
        }
    } else {
        float c0[4] = {}, c1[4] = {};
        #pragma unroll
        for (int ct = 0; ct < 4; ++ct) {
            int col = wcol + ct * 16 + lrow;
            float w0 = cls_w[col], w1 = cls_w[DD + col];
            #pragma unroll
            for (int r = 0; r < 4; ++r) {
                c0[r] += ln2v[ct][r] * w0;
                c1[r] += ln2v[ct][r] * w1;
            }
        }
        #pragma unroll
        for (int off = 1; off < 16; off <<= 1) {
            #pragma unroll
            for (int r = 0; r < 4; ++r) {
                c0[r] += __shfl_xor(c0[r], off);
                c1[r] += __shfl_xor(c1[r], off);
            }
        }
        if (lrow == 0) {
            #pragma unroll
            for (int r = 0; r < 4; ++r) {
                redc[0][wave][lk * 4 + r] = c0[r];
                redc[1][wave][lk * 4 + r] = c1[r];
            }
        }
        __syncthreads();
        if (wave == 0 && lrow == 0) {
            float cb0 = cls_b[0], cb1 = cls_b[1];
            #pragma unroll
            for (int r = 0; r < 4; ++r) {
                int rr = lk * 4 + r;
                float o0 = redc[0][0][rr] + redc[0][1][rr] + redc[0][2][rr] + redc[0][3][rr];
                float o1 = redc[1][0][rr] + redc[1][1][rr] + redc[1][2][rr] + redc[1][3][rr];
                out[(brow + rr) * 2]     = o0 + cb0;
                out[(brow + rr) * 2 + 1] = o1 + cb1;
            }
        }
    }
}

// ---------------- MFMA flash attention (single-chunk, paired V staging) ----------------
__global__ __launch_bounds__(256)
void aml_attn_k(const u16* __restrict__ qkv, const int* __restrict__ offs,
                u16* __restrict__ o) {
    int tb = blockIdx.x, head = blockIdx.y, z = blockIdx.z;
    int start = offs[tb], end = offs[tb + 1];
    int S = end - start;
    if (S <= z * 64) return;
    int t = threadIdx.x, wave = t >> 6, lane = t & 63;
    int lq = lane & 15, lk = lane >> 4;
    int qoff = head * 64;

    __shared__ __align__(16) unsigned char Kl[8192];
    __shared__ __align__(16) unsigned char Vt[8192];
    __shared__ __align__(16) unsigned char Pl[4][2048];
    __shared__ float Ol[4][16][65];

    int qi = start + z * 64 + wave * 16 + lq;
    int qic = min(qi, end - 1);
    const u16* qp = qkv + (size_t)qic * 768 + qoff + lk * 8;
    short8 qf[2];
    qf[0] = *(const short8*)qp;
    qf[1] = *(const short8*)(qp + 32);

    float m = -1e30f, l = 0.f;
    f32x4 acc[4] = {};

    int ntile = (S + 63) >> 6;
    for (int tile = 0; tile < ntile; ++tile) {
        int jcnt = S - tile * 64; if (jcnt > 64) jcnt = 64;
        {
            int j = t >> 2, d0 = (t & 3) * 16;
            unsigned char* krow = Kl + j * 128;
            if (j < jcnt) {
                const u16* kp = qkv + (size_t)(start + tile * 64 + j) * 768 + 256 + qoff + d0;
                *(uint4*)(krow + ((d0 * 2) ^ ((j & 7) << 4))) = *(const uint4*)kp;
                *(uint4*)(krow + ((d0 * 2 + 16) ^ ((j & 7) << 4))) = *(const uint4*)(kp + 8);
            } else {
                uint4 zz = { 0, 0, 0, 0 };
                *(uint4*)(krow + ((d0 * 2) ^ ((j & 7) << 4))) = zz;
                *(uint4*)(krow + ((d0 * 2 + 16) ^ ((j & 7) << 4))) = zz;
            }
        }
        {
            int j0 = (t & 31) * 2, d0v = (t >> 5) * 8;
            const u16* vbase = qkv + (size_t)(start + tile * 64) * 768 + 512 + qoff + d0v;
            uint4 va = { 0, 0, 0, 0 }, vb = { 0, 0, 0, 0 };
            if (j0 < jcnt)     va = *(const uint4*)(vbase + (size_t)j0 * 768);
            if (j0 + 1 < jcnt) vb = *(const uint4*)(vbase + (size_t)(j0 + 1) * 768);
            const u16* pa = (const u16*)&va;
            const u16* pb = (const u16*)&vb;
            #pragma unroll
            for (int i = 0; i < 8; ++i) {
                int d = d0v + i;
                unsigned w = (unsigned)pa[i] | ((unsigned)pb[i] << 16);
                *(unsigned*)(Vt + d * 128 + ((j0 * 2) ^ ((d & 7) << 4))) = w;
            }
        }
        __syncthreads();

        f32x4 sv[4];
        #pragma unroll
        for (int kt = 0; kt < 4; ++kt) {
            int kr = kt * 16 + lq;
            f32x4 s = {};
            #pragma unroll
            for (int ks = 0; ks < 2; ++ks) {
                short8 kf = *(const short8*)(Kl + kr * 128 + ((ks * 64 + lk * 16) ^ ((kr & 7) << 4)));
                s = __builtin_amdgcn_mfma_f32_16x16x32_bf16(kf, qf[ks], s, 0, 0, 0);
            }
            sv[kt] = s;
        }
        float pm = -1e30f;
        #pragma unroll
        for (int kt = 0; kt < 4; ++kt) {
            #pragma unroll
            for (int r = 0; r < 4; ++r) {
                int kk = tile * 64 + kt * 16 + lk * 4 + r;
                float s = (kk < S) ? sv[kt][r] * 0.125f : -1e30f;
                sv[kt][r] = s;
                pm = fmaxf(pm, s);
            }
        }
        pm = fmaxf(pm, __shfl_xor(pm, 16));
        pm = fmaxf(pm, __shfl_xor(pm, 32));
        float mn = fmaxf(m, pm);
        float corr = __expf(m - mn);
        m = mn;
        float ps = 0.f;
        #pragma unroll
        for (int kt = 0; kt < 4; ++kt) {
            #pragma unroll
            for (int r = 0; r < 4; ++r) {
                float p = __expf(sv[kt][r] - mn);
                sv[kt][r] = p;
                ps += p;
            }
            uint2 w = { pk2(sv[kt][0], sv[kt][1]), pk2(sv[kt][2], sv[kt][3]) };
            *(uint2*)(Pl[wave] + lq * 128 + ((kt * 32 + lk * 8) ^ ((lq & 7) << 4))) = w;
        }
        ps += __shfl_xor(ps, 16);
        ps += __shfl_xor(ps, 32);
        l = l * corr + ps;
        #pragma unroll
        for (int dt = 0; dt < 4; ++dt) {
            #pragma unroll
            for (int r = 0; r < 4; ++r) acc[dt][r] *= corr;
        }
        #pragma unroll
        for (int ks = 0; ks < 2; ++ks) {
            short8 pf = *(const short8*)(Pl[wave] + lq * 128 + ((ks * 64 + lk * 16) ^ ((lq & 7) << 4)));
            #pragma unroll
            for (int dt = 0; dt < 4; ++dt) {
                int dr = dt * 16 + lq;
                short8 vf = *(const short8*)(Vt + dr * 128 + ((ks * 64 + lk * 16) ^ ((dr & 7) << 4)));
                acc[dt] = __builtin_amdgcn_mfma_f32_16x16x32_bf16(vf, pf, acc[dt], 0, 0, 0);
            }
        }
        __syncthreads();
    }

    float linv = 1.0f / l;
    #pragma unroll
    for (int dt = 0; dt < 4; ++dt) {
        #pragma unroll
        for (int r = 0; r < 4; ++r)
            Ol[wave][lq][dt * 16 + lk * 4 + r] = acc[dt][r] * linv;
    }
    int q2 = lane >> 2, c2 = lane & 3;
    int qg = start + z * 64 + wave * 16 + q2;
    if (qg < end) {
        u16* op = o + (size_t)qg * DD + qoff + c2 * 16;
        const float* sp = &Ol[wave][q2][c2 * 16];
        #pragma unroll
        for (int i = 0; i < 8; ++i)
            ((unsigned*)op)[i] = pk2(sp[2 * i], sp[2 * i + 1]);
    }
}

extern "C" void kernel_launch(void* const* d_in, const int* in_sizes, int n_in,
                              void* d_out, int out_size, void* d_ws, size_t ws_size,
                              hipStream_t stream) {
    const float* x       = (const float*)d_in[0];
    const int*   ei      = (const int*)d_in[1];
    const int*   ts      = (const int*)d_in[2];
    const float* lin_l_w = (const float*)d_in[3];
    const float* lin_l_b = (const float*)d_in[4];
    const float* lin_r_w = (const float*)d_in[5];
    const float* bn_g    = (const float*)d_in[6];
    const float* bn_b    = (const float*)d_in[7];
    const float* inp_w   = (const float*)d_in[8];
    const float* inp_b   = (const float*)d_in[9];
    const float* out_w   = (const float*)d_in[10];
    const float* out_b   = (const float*)d_in[11];
    const float* ff1_w   = (const float*)d_in[12];
    const float* ff1_b   = (const float*)d_in[13];
    const float* ff2_w   = (const float*)d_in[14];
    const float* ff2_b   = (const float*)d_in[15];
    const float* ln1_g   = (const float*)d_in[16];
    const float* ln1_b   = (const float*)d_in[17];
    const float* ln2_g   = (const float*)d_in[18];
    const float* ln2_b   = (const float*)d_in[19];
    const float* cls_w   = (const float*)d_in[20];
    const float* cls_b   = (const float*)d_in[21];

    float* ws     = (float*)d_ws;
    float* stats  = ws;
    int*   deg    = (int*)(stats + 512);
    int*   rowptr = deg + NN;
    int*   cursor = rowptr + NN + 4;
    int*   eid    = cursor + NN;
    int*   offs   = eid + EE;
    u16*   wb     = (u16*)(offs + 64);
    u16*   hb     = wb + (size_t)WROWS * 256;
    float* h2     = (float*)(hb + (size_t)NN * DD);
    u16*   qkv    = (u16*)(h2 + (size_t)NN * DD);
    u16*   t1     = qkv + (size_t)NN * 768;
    u16*   ac     = qkv;

    const u16* wb_cat = wb;
    const u16* wb_inp[2] = { wb + (size_t)(256) * 256,        wb + (size_t)(256 + 1536) * 256 };
    const u16* wb_out[2] = { wb + (size_t)(256 + 768) * 256,  wb + (size_t)(256 + 1536 + 768) * 256 };
    const u16* wb_ff1[2] = { wb + (size_t)(256 + 1024) * 256, wb + (size_t)(256 + 1536 + 1024) * 256 };
    const u16* wb_ff2[2] = { wb + (size_t)(256 + 1280) * 256, wb + (size_t)(256 + 1536 + 1280) * 256 };

    aml_prep_k<<<WROWS + 27, 256, 0, stream>>>(lin_l_w, lin_r_w, inp_w, out_w, ff1_w, ff2_w,
                                               ts, wb, offs, stats);
    aml_hist_k<<<EE / 256, 256, 0, stream>>>(ei, deg);
    aml_scan_k<<<1, 256, 0, stream>>>(deg, rowptr, cursor);
    aml_scatter2_k<<<EE / 256, 256, 0, stream>>>(ei, cursor, eid);
    aml_gather_k<<<NN / 4, 256, 0, stream>>>(x, rowptr, eid, ac);
    // SAGE: CT2=1, 384 blocks
    aml_gemm_k<0, 0, 0, 1, 1><<<dim3(NN / 64, 4), 256, 0, stream>>>(
        ac, wb_cat, lin_l_b, hb, DD, stats, nullptr, nullptr, nullptr);
    // qkv-l0: CT2=1, 1152 blocks; BN+ReLU in staging (y==0 writes h2)
    aml_gemm_k<0, 2, 0, 0, 1><<<dim3(NN / 64, 12), 256, 0, stream>>>(
        hb, wb_inp[0], inp_b, qkv, 768, stats, bn_g, bn_b, h2);

    // layer 0
    aml_attn_k<<<dim3(TT, NH, ATTN_Z), 256, 0, stream>>>(qkv, offs, t1);
    aml_tail_k<0><<<NN / 16, 256, 0, stream>>>(
        t1, h2, wb_out[0], out_b, ln1_g, ln1_b,
        wb_ff1[0], ff1_b, wb_ff2[0], ff2_b, ln2_g, ln2_b,
        wb_inp[1], inp_b + 768, qkv, nullptr, nullptr, nullptr);

    // layer 1
    aml_attn_k<<<dim3(TT, NH, ATTN_Z), 256, 0, stream>>>(qkv, offs, t1);
    aml_tail_k<1><<<NN / 16, 256, 0, stream>>>(
        t1, h2, wb_out[1], out_b + DD, ln1_g + DD, ln1_b + DD,
        wb_ff1[1], ff1_b + DD, wb_ff2[1], ff2_b + DD, ln2_g + DD, ln2_b + DD,
        nullptr, nullptr, nullptr, cls_w, cls_b, (float*)d_out);
}